// Round 1
// baseline (6734.145 us; speedup 1.0000x reference)
//
#include <hip/hip_runtime.h>
#include <math.h>

#define BATCH 2
#define SEQLEN 1024
#define NTOK 2048            // BATCH*SEQLEN
#define DIN 768
#define DM 1536
#define DS 16
#define DD 96
#define EPS 1e-6f

// ---------------- embedding gather ----------------
__global__ __launch_bounds__(192) void embed_kernel(const int* __restrict__ tok,
                                                    const float* __restrict__ emb,
                                                    float* __restrict__ seq) {
    int m = blockIdx.x;
    int t = tok[m];
    const float4* src = (const float4*)(emb + (size_t)t * DIN);
    float4* dst = (float4*)(seq + (size_t)m * DIN);
    dst[threadIdx.x] = src[threadIdx.x];
}

// ---------------- rmsnorm (one block per token) ----------------
__global__ __launch_bounds__(256) void rmsnorm_kernel(const float* __restrict__ in,
                                                      const float* __restrict__ w,
                                                      float* __restrict__ out) {
    int m = blockIdx.x;
    const float* x = in + (size_t)m * DIN;
    float v[3];
    float s = 0.f;
#pragma unroll
    for (int j = 0; j < 3; j++) {
        v[j] = x[threadIdx.x + 256 * j];
        s += v[j] * v[j];
    }
#pragma unroll
    for (int off = 32; off; off >>= 1) s += __shfl_down(s, off);
    __shared__ float wsum[4];
    int lane = threadIdx.x & 63, wv = threadIdx.x >> 6;
    if (lane == 0) wsum[wv] = s;
    __syncthreads();
    float tot = wsum[0] + wsum[1] + wsum[2] + wsum[3];
    float scale = rsqrtf(tot / (float)DIN + EPS);
#pragma unroll
    for (int j = 0; j < 3; j++) {
        int c = threadIdx.x + 256 * j;
        out[(size_t)m * DIN + c] = v[j] * scale * w[c];
    }
}

// ---------------- tiled fp32 GEMM, C[M,N] = A[M,K] @ B[N,K]^T ----------------
// EPI: 0 = store, 1 = softplus(acc + bias[n]), 2 = C += acc (residual)
template <int EPI>
__global__ __launch_bounds__(256) void gemm_nt(const float* __restrict__ A,
                                               const float* __restrict__ B,
                                               float* __restrict__ C, int N, int K,
                                               const float* __restrict__ bias) {
    __shared__ float As[16][68];
    __shared__ float Bs[16][68];
    int tid = threadIdx.x;
    int lr = tid >> 2;            // 0..63 row within tile
    int lk = (tid & 3) << 2;      // 0,4,8,12
    const float* Aptr = A + (size_t)(blockIdx.y * 64 + lr) * K + lk;
    const float* Bptr = B + (size_t)(blockIdx.x * 64 + lr) * K + lk;
    int tx = tid & 15, ty = tid >> 4;
    float acc[4][4] = {};
    for (int k0 = 0; k0 < K; k0 += 16) {
        float4 av = *(const float4*)(Aptr + k0);
        float4 bv = *(const float4*)(Bptr + k0);
        __syncthreads();
        As[lk + 0][lr] = av.x; As[lk + 1][lr] = av.y;
        As[lk + 2][lr] = av.z; As[lk + 3][lr] = av.w;
        Bs[lk + 0][lr] = bv.x; Bs[lk + 1][lr] = bv.y;
        Bs[lk + 2][lr] = bv.z; Bs[lk + 3][lr] = bv.w;
        __syncthreads();
#pragma unroll
        for (int kk = 0; kk < 16; kk++) {
            float4 a4 = *(const float4*)&As[kk][ty * 4];
            float4 b4 = *(const float4*)&Bs[kk][tx * 4];
            float aa[4] = {a4.x, a4.y, a4.z, a4.w};
            float bb[4] = {b4.x, b4.y, b4.z, b4.w};
#pragma unroll
            for (int i = 0; i < 4; i++)
#pragma unroll
                for (int j = 0; j < 4; j++)
                    acc[i][j] = fmaf(aa[i], bb[j], acc[i][j]);
        }
    }
    int row0 = blockIdx.y * 64 + ty * 4;
    int col0 = blockIdx.x * 64 + tx * 4;
    float4 bsv = make_float4(0.f, 0.f, 0.f, 0.f);
    if (EPI == 1) bsv = *(const float4*)(bias + col0);
#pragma unroll
    for (int i = 0; i < 4; i++) {
        float* cp = C + (size_t)(row0 + i) * N + col0;
        float r[4];
        if (EPI == 0) {
#pragma unroll
            for (int j = 0; j < 4; j++) r[j] = acc[i][j];
        } else if (EPI == 1) {
            float bb[4] = {bsv.x, bsv.y, bsv.z, bsv.w};
#pragma unroll
            for (int j = 0; j < 4; j++) {
                float xv = acc[i][j] + bb[j];
                r[j] = fmaxf(xv, 0.f) + log1pf(expf(-fabsf(xv)));   // softplus
            }
        } else {
            float4 old = *(const float4*)cp;
            float oo[4] = {old.x, old.y, old.z, old.w};
#pragma unroll
            for (int j = 0; j < 4; j++) r[j] = acc[i][j] + oo[j];
        }
        *(float4*)cp = make_float4(r[0], r[1], r[2], r[3]);
    }
}

// ---------------- depthwise causal conv (K=4) + silu ----------------
__global__ __launch_bounds__(256) void conv_silu_kernel(const float* __restrict__ ab,
                                                        const float* __restrict__ cw,
                                                        const float* __restrict__ cb,
                                                        float* __restrict__ out) {
    int idx = blockIdx.x * 256 + threadIdx.x;   // < NTOK*DM
    int c = idx % DM;
    int t = idx / DM;
    int l = t % SEQLEN;
    float4 w4 = ((const float4*)cw)[c];         // cw[c][0..3]
    float y = cb[c];
    y = fmaf(w4.w, ab[(size_t)t * (2 * DM) + c], y);
    if (l >= 1) y = fmaf(w4.z, ab[(size_t)(t - 1) * (2 * DM) + c], y);
    if (l >= 2) y = fmaf(w4.y, ab[(size_t)(t - 2) * (2 * DM) + c], y);
    if (l >= 3) y = fmaf(w4.x, ab[(size_t)(t - 3) * (2 * DM) + c], y);
    out[(size_t)t * DM + c] = y / (1.f + expf(-y));   // silu
}

// ---------------- fused B, C, dt0 projections (one block per token) ----------------
__global__ __launch_bounds__(128) void bcd_kernel(const float* __restrict__ a,
                                                  const float* __restrict__ sB,
                                                  const float* __restrict__ sC,
                                                  const float* __restrict__ sD0,
                                                  float* __restrict__ Bm, float* __restrict__ Cm,
                                                  float* __restrict__ dt0) {
    __shared__ float av[DM];
    int m = blockIdx.x, tid = threadIdx.x;
    const float4* src = (const float4*)(a + (size_t)m * DM);
#pragma unroll
    for (int j = 0; j < 3; j++) ((float4*)av)[tid + 128 * j] = src[tid + 128 * j];
    __syncthreads();
    const float* wrow;
    if (tid < 16) wrow = sB + (size_t)tid * DM;
    else if (tid < 32) wrow = sC + (size_t)(tid - 16) * DM;
    else wrow = sD0 + (size_t)(tid - 32) * DM;
    float sum = 0.f;
    for (int k = 0; k < DM; k += 4) {
        float4 w4 = *(const float4*)(wrow + k);
        sum = fmaf(av[k], w4.x, sum);
        sum = fmaf(av[k + 1], w4.y, sum);
        sum = fmaf(av[k + 2], w4.z, sum);
        sum = fmaf(av[k + 3], w4.w, sum);
    }
    if (tid < 16) Bm[m * DS + tid] = sum;
    else if (tid < 32) Cm[m * DS + tid - 16] = sum;
    else dt0[m * DD + tid - 32] = sum;
}

// ---------------- selective scan + gate ----------------
// thread layout: 16 s-lanes contiguous, 16 d-channels per block (256 threads)
__global__ __launch_bounds__(256) void scan_kernel(const float* __restrict__ delta,
                                                   const float* __restrict__ a,
                                                   const float* __restrict__ Bm,
                                                   const float* __restrict__ Cm,
                                                   const float* __restrict__ ab,
                                                   const float* __restrict__ A_log,
                                                   const float* __restrict__ Dp,
                                                   float* __restrict__ y1) {
    int b = blockIdx.x / (DM / 16);
    int dblk = blockIdx.x % (DM / 16);
    int s = threadIdx.x & 15;
    int dl = threadIdx.x >> 4;
    int d = dblk * 16 + dl;
    float An = -expf(A_log[d * DS + s]);
    float Dv = Dp[d];
    float h = 0.f;
    for (int l = 0; l < SEQLEN; l++) {
        int t = b * SEQLEN + l;
        float dv = delta[(size_t)t * DM + d];
        float avv = a[(size_t)t * DM + d];
        float Bv = Bm[t * DS + s];
        float Cv = Cm[t * DS + s];
        h = expf(dv * An) * h + dv * Bv * avv;
        float contrib = h * Cv;
#pragma unroll
        for (int mk = 8; mk; mk >>= 1) contrib += __shfl_xor(contrib, mk);
        if (s == 0) {
            float bg = ab[(size_t)t * (2 * DM) + DM + d];
            float sl = bg / (1.f + expf(-bg));
            y1[(size_t)t * DM + d] = (contrib + Dv * avv) * sl;
        }
    }
}

extern "C" void kernel_launch(void* const* d_in, const int* in_sizes, int n_in,
                              void* d_out, int out_size, void* d_ws, size_t ws_size,
                              hipStream_t stream) {
    const int* tok       = (const int*)d_in[0];
    const float* emb     = (const float*)d_in[1];
    const float* in_proj = (const float*)d_in[2];   // (4, 3072, 768)
    const float* out_proj= (const float*)d_in[3];   // (4, 768, 1536)
    const float* sB      = (const float*)d_in[4];   // (4, 16, 1536)
    const float* sC      = (const float*)d_in[5];   // (4, 16, 1536)
    const float* sD0     = (const float*)d_in[6];   // (4, 96, 1536)
    const float* sD1     = (const float*)d_in[7];   // (4, 1536, 96)
    const float* sD1b    = (const float*)d_in[8];   // (4, 1536)
    const float* cw      = (const float*)d_in[9];   // (4, 1536, 4)
    const float* cb      = (const float*)d_in[10];  // (4, 1536)
    const float* A_log   = (const float*)d_in[11];  // (4, 1536, 16)
    const float* Dp      = (const float*)d_in[12];  // (4, 1536)
    const float* norm_w  = (const float*)d_in[13];  // (4, 768)
    const float* norm_f  = (const float*)d_in[14];  // (768,)
    const float* head_w  = (const float*)d_in[15];  // (32000, 768)
    float* out = (float*)d_out;

    float* p = (float*)d_ws;
    float* seq  = p; p += NTOK * DIN;        // 6.3 MB
    float* xn   = p; p += NTOK * DIN;        // 6.3 MB
    float* ab   = p; p += NTOK * 2 * DM;     // 25.2 MB
    float* ac   = p; p += NTOK * DM;         // 12.6 MB
    float* Bmb  = p; p += NTOK * DS;
    float* Cmb  = p; p += NTOK * DS;
    float* dt0  = p; p += NTOK * DD;
    float* delta= p; p += NTOK * DM;         // 12.6 MB
    float* y1   = p; p += NTOK * DM;         // 12.6 MB

    embed_kernel<<<NTOK, 192, 0, stream>>>(tok, emb, seq);
    for (int i = 0; i < 4; i++) {
        rmsnorm_kernel<<<NTOK, 256, 0, stream>>>(seq, norm_w + i * DIN, xn);
        gemm_nt<0><<<dim3(2 * DM / 64, NTOK / 64), 256, 0, stream>>>(
            xn, in_proj + (size_t)i * 2 * DM * DIN, ab, 2 * DM, DIN, nullptr);
        conv_silu_kernel<<<NTOK * DM / 256, 256, 0, stream>>>(
            ab, cw + (size_t)i * DM * 4, cb + (size_t)i * DM, ac);
        bcd_kernel<<<NTOK, 128, 0, stream>>>(
            ac, sB + (size_t)i * DS * DM, sC + (size_t)i * DS * DM,
            sD0 + (size_t)i * DD * DM, Bmb, Cmb, dt0);
        gemm_nt<1><<<dim3(DM / 64, NTOK / 64), 256, 0, stream>>>(
            dt0, sD1 + (size_t)i * DM * DD, delta, DM, DD, sD1b + (size_t)i * DM);
        scan_kernel<<<BATCH * (DM / 16), 256, 0, stream>>>(
            delta, ac, Bmb, Cmb, ab, A_log + (size_t)i * DM * DS, Dp + (size_t)i * DM, y1);
        gemm_nt<2><<<dim3(DIN / 64, NTOK / 64), 256, 0, stream>>>(
            y1, out_proj + (size_t)i * DIN * DM, seq, DIN, DM, nullptr);
    }
    rmsnorm_kernel<<<NTOK, 256, 0, stream>>>(seq, norm_f, xn);
    gemm_nt<0><<<dim3(32000 / 64, NTOK / 64), 256, 0, stream>>>(
        xn, head_w, out, 32000, DIN, nullptr);
}

// Round 2
// 1700.598 us; speedup vs baseline: 3.9599x; 3.9599x over previous
//
#include <hip/hip_runtime.h>
#include <math.h>

#define BATCH 2
#define SEQLEN 1024
#define NTOK 2048            // BATCH*SEQLEN
#define DIN 768
#define DM 1536
#define DS 16
#define DD 96
#define EPS 1e-6f
#define NC 32                // scan chunks
#define CL 32                // chunk length (NC*CL == SEQLEN)
#define NG (BATCH*DM*DS)     // 49152 independent recurrences

typedef __attribute__((ext_vector_type(8))) short short8;
typedef __attribute__((ext_vector_type(4))) float f32x4;

static __device__ __forceinline__ unsigned short f2bf(float f) {
    unsigned int u = __float_as_uint(f);
    u += 0x7fff + ((u >> 16) & 1);           // round-to-nearest-even
    return (unsigned short)(u >> 16);
}

// ---------------- embedding gather ----------------
__global__ __launch_bounds__(192) void embed_kernel(const int* __restrict__ tok,
                                                    const float* __restrict__ emb,
                                                    float* __restrict__ seq) {
    int m = blockIdx.x;
    int t = tok[m];
    const float4* src = (const float4*)(emb + (size_t)t * DIN);
    float4* dst = (float4*)(seq + (size_t)m * DIN);
    dst[threadIdx.x] = src[threadIdx.x];
}

// ---------------- fp32 -> bf16 casts ----------------
__global__ __launch_bounds__(256) void cast_kernel(const float* __restrict__ in,
                                                   unsigned short* __restrict__ out, int n4) {
    int i = blockIdx.x * 256 + threadIdx.x;
    if (i < n4) {
        float4 v = ((const float4*)in)[i];
        ushort4 r;
        r.x = f2bf(v.x); r.y = f2bf(v.y); r.z = f2bf(v.z); r.w = f2bf(v.w);
        ((ushort4*)out)[i] = r;
    }
}

// concat sB(16 rows) + sC(16) + sD0(96) per layer -> [4][128][DM] bf16
__global__ __launch_bounds__(256) void wcat_kernel(const float* __restrict__ sB,
                                                   const float* __restrict__ sC,
                                                   const float* __restrict__ sD0,
                                                   unsigned short* __restrict__ out) {
    int idx = blockIdx.x * 256 + threadIdx.x;       // 4*128*DM total
    int k = idx % DM;
    int row = (idx / DM) & 127;
    int layer = idx / (DM * 128);
    float v;
    if (row < 16)      v = sB[((size_t)layer * 16 + row) * DM + k];
    else if (row < 32) v = sC[((size_t)layer * 16 + (row - 16)) * DM + k];
    else               v = sD0[((size_t)layer * 96 + (row - 32)) * DM + k];
    out[idx] = f2bf(v);
}

// ---------------- rmsnorm (one block per token), bf16 out ----------------
__global__ __launch_bounds__(256) void rmsnorm_kernel(const float* __restrict__ in,
                                                      const float* __restrict__ w,
                                                      unsigned short* __restrict__ out) {
    int m = blockIdx.x;
    const float* x = in + (size_t)m * DIN;
    float v[3];
    float s = 0.f;
#pragma unroll
    for (int j = 0; j < 3; j++) {
        v[j] = x[threadIdx.x + 256 * j];
        s += v[j] * v[j];
    }
#pragma unroll
    for (int off = 32; off; off >>= 1) s += __shfl_down(s, off);
    __shared__ float wsum[4];
    int lane = threadIdx.x & 63, wv = threadIdx.x >> 6;
    if (lane == 0) wsum[wv] = s;
    __syncthreads();
    float tot = wsum[0] + wsum[1] + wsum[2] + wsum[3];
    float scale = rsqrtf(tot / (float)DIN + EPS);
#pragma unroll
    for (int j = 0; j < 3; j++) {
        int c = threadIdx.x + 256 * j;
        out[(size_t)m * DIN + c] = f2bf(v[j] * scale * w[c]);
    }
}

// ---------------- bf16 MFMA GEMM: C[M,N] = A[M,K] @ B[N,K]^T, fp32 out ----------------
// 128x128 block tile, BK=32, 4 waves, each wave 64x64 via 4x4 of 16x16x32 MFMA.
// EPI: 0 = store, 1 = C += acc (residual)
template <int EPI>
__global__ __launch_bounds__(256) void gemm_mfma(const unsigned short* __restrict__ A,
                                                 const unsigned short* __restrict__ B,
                                                 float* __restrict__ C, int N, int K) {
    __shared__ unsigned short As[128 * 32];
    __shared__ unsigned short Bs[128 * 32];
    int tid = threadIdx.x;
    int lane = tid & 63, w = tid >> 6;
    int wm = w >> 1, wn = w & 1;
    int fm = lane & 15, fk = lane >> 4;
    const unsigned short* Ab = A + (size_t)blockIdx.y * 128 * K;
    const unsigned short* Bb = B + (size_t)blockIdx.x * 128 * K;
    int r0 = tid >> 2;                // staging row (chunk id c = tid: row=c>>2)
    int ko = (tid & 3) * 8;           // 8 bf16 = 16 B per chunk
    f32x4 acc[4][4];
#pragma unroll
    for (int i = 0; i < 4; i++)
#pragma unroll
        for (int j = 0; j < 4; j++) acc[i][j] = (f32x4){0.f, 0.f, 0.f, 0.f};

    for (int k0 = 0; k0 < K; k0 += 32) {
        __syncthreads();   // previous iter's LDS reads must finish before overwrite
#pragma unroll
        for (int j = 0; j < 2; j++) {
            int row = r0 + j * 64;
            int c = tid + j * 256;
            __builtin_amdgcn_global_load_lds(
                (const __attribute__((address_space(1))) unsigned int*)(const void*)(Ab + (size_t)row * K + k0 + ko),
                (__attribute__((address_space(3))) unsigned int*)(void*)(As + c * 8), 16, 0, 0);
            __builtin_amdgcn_global_load_lds(
                (const __attribute__((address_space(1))) unsigned int*)(const void*)(Bb + (size_t)row * K + k0 + ko),
                (__attribute__((address_space(3))) unsigned int*)(void*)(Bs + c * 8), 16, 0, 0);
        }
        __syncthreads();   // drains vmcnt -> staging visible

        short8 af[4], bfv[4];
#pragma unroll
        for (int i = 0; i < 4; i++)
            af[i] = *(const short8*)(As + (wm * 64 + i * 16 + fm) * 32 + fk * 8);
#pragma unroll
        for (int j = 0; j < 4; j++)
            bfv[j] = *(const short8*)(Bs + (wn * 64 + j * 16 + fm) * 32 + fk * 8);
#pragma unroll
        for (int i = 0; i < 4; i++)
#pragma unroll
            for (int j = 0; j < 4; j++)
                acc[i][j] = __builtin_amdgcn_mfma_f32_16x16x32_bf16(af[i], bfv[j], acc[i][j], 0, 0, 0);
    }

    int rowb = blockIdx.y * 128 + wm * 64;
    int colb = blockIdx.x * 128 + wn * 64;
#pragma unroll
    for (int i = 0; i < 4; i++)
#pragma unroll
        for (int j = 0; j < 4; j++)
#pragma unroll
            for (int r = 0; r < 4; r++) {
                int row = rowb + i * 16 + fk * 4 + r;   // C/D: col=lane&15, row=(lane>>4)*4+reg
                int col = colb + j * 16 + fm;
                size_t off = (size_t)row * N + col;
                if (EPI == 0) C[off] = acc[i][j][r];
                else          C[off] += acc[i][j][r];
            }
}

// ---------------- depthwise causal conv (K=4) + silu, fp32+bf16 out ----------------
__global__ __launch_bounds__(256) void conv_silu_kernel(const float* __restrict__ ab,
                                                        const float* __restrict__ cw,
                                                        const float* __restrict__ cb,
                                                        float* __restrict__ out,
                                                        unsigned short* __restrict__ outb) {
    int idx = blockIdx.x * 256 + threadIdx.x;   // < NTOK*DM
    int c = idx % DM;
    int t = idx / DM;
    int l = t % SEQLEN;
    float4 w4 = ((const float4*)cw)[c];
    float y = cb[c];
    y = fmaf(w4.w, ab[(size_t)t * (2 * DM) + c], y);
    if (l >= 1) y = fmaf(w4.z, ab[(size_t)(t - 1) * (2 * DM) + c], y);
    if (l >= 2) y = fmaf(w4.y, ab[(size_t)(t - 2) * (2 * DM) + c], y);
    if (l >= 3) y = fmaf(w4.x, ab[(size_t)(t - 3) * (2 * DM) + c], y);
    float sv = y / (1.f + expf(-y));
    out[(size_t)t * DM + c] = sv;
    outb[(size_t)t * DM + c] = f2bf(sv);
}

// ---------------- fp32 GEMM w/ softplus epilogue (delta), 64x64 tile ----------------
__global__ __launch_bounds__(256) void gemm32_softplus(const float* __restrict__ A, int lda,
                                                       const float* __restrict__ B,
                                                       float* __restrict__ C, int N, int K,
                                                       const float* __restrict__ bias) {
    __shared__ float As[16][68];
    __shared__ float Bs[16][68];
    int tid = threadIdx.x;
    int lr = tid >> 2;
    int lk = (tid & 3) << 2;
    const float* Aptr = A + (size_t)(blockIdx.y * 64 + lr) * lda + lk;
    const float* Bptr = B + (size_t)(blockIdx.x * 64 + lr) * K + lk;
    int tx = tid & 15, ty = tid >> 4;
    float acc[4][4] = {};
    for (int k0 = 0; k0 < K; k0 += 16) {
        float4 av = *(const float4*)(Aptr + k0);
        float4 bv = *(const float4*)(Bptr + k0);
        __syncthreads();
        As[lk + 0][lr] = av.x; As[lk + 1][lr] = av.y;
        As[lk + 2][lr] = av.z; As[lk + 3][lr] = av.w;
        Bs[lk + 0][lr] = bv.x; Bs[lk + 1][lr] = bv.y;
        Bs[lk + 2][lr] = bv.z; Bs[lk + 3][lr] = bv.w;
        __syncthreads();
#pragma unroll
        for (int kk = 0; kk < 16; kk++) {
            float4 a4 = *(const float4*)&As[kk][ty * 4];
            float4 b4 = *(const float4*)&Bs[kk][tx * 4];
            float aa[4] = {a4.x, a4.y, a4.z, a4.w};
            float bb[4] = {b4.x, b4.y, b4.z, b4.w};
#pragma unroll
            for (int i = 0; i < 4; i++)
#pragma unroll
                for (int j = 0; j < 4; j++)
                    acc[i][j] = fmaf(aa[i], bb[j], acc[i][j]);
        }
    }
    int row0 = blockIdx.y * 64 + ty * 4;
    int col0 = blockIdx.x * 64 + tx * 4;
    float4 bsv = *(const float4*)(bias + col0);
    float bb[4] = {bsv.x, bsv.y, bsv.z, bsv.w};
#pragma unroll
    for (int i = 0; i < 4; i++) {
        float* cp = C + (size_t)(row0 + i) * N + col0;
        float r[4];
#pragma unroll
        for (int j = 0; j < 4; j++) {
            float xv = acc[i][j] + bb[j];
            r[j] = fmaxf(xv, 0.f) + log1pf(expf(-fabsf(xv)));   // softplus
        }
        *(float4*)cp = make_float4(r[0], r[1], r[2], r[3]);
    }
}

// ---------------- selective scan, 3-phase chunked ----------------
// Phase 1: per (b,d,s,chunk) compute P = prod(exp(dv*A)), S = chunk-local scan end state.
__global__ __launch_bounds__(256) void scan_chunk(const float* __restrict__ delta,
                                                  const float* __restrict__ a,
                                                  const float* __restrict__ bcd,
                                                  const float* __restrict__ A_log,
                                                  float* __restrict__ P, float* __restrict__ S) {
    int bid = blockIdx.x;
    int c = bid & (NC - 1);
    int dblk = (bid >> 5) % (DM / 16);
    int b = bid / (NC * (DM / 16));
    int s = threadIdx.x & 15, dl = threadIdx.x >> 4;
    int d = dblk * 16 + dl;
    float An = -expf(A_log[d * DS + s]);
    float Pv = 1.f, Sv = 0.f;
    int t0 = b * SEQLEN + c * CL;
    for (int l = 0; l < CL; l++) {
        int t = t0 + l;
        float dv = delta[(size_t)t * DM + d];
        float av = a[(size_t)t * DM + d];
        float Bv = bcd[t * 128 + s];
        float e = expf(dv * An);
        Pv *= e;
        Sv = e * Sv + dv * Bv * av;
    }
    int g = (b * DM + d) * 16 + s;
    P[c * NG + g] = Pv;
    S[c * NG + g] = Sv;
}

// Phase 2: serial combine over the 32 chunk summaries -> h_init per chunk.
__global__ __launch_bounds__(256) void scan_combine(const float* __restrict__ P,
                                                    const float* __restrict__ S,
                                                    float* __restrict__ Hb) {
    int g = blockIdx.x * 256 + threadIdx.x;
    float h = 0.f;
#pragma unroll
    for (int c = 0; c < NC; c++) {
        Hb[c * NG + g] = h;
        h = P[c * NG + g] * h + S[c * NG + g];
    }
}

// Phase 3: re-apply with correct h_init; fuse C-reduction, D-skip, silu gate; write y fp32+bf16.
__global__ __launch_bounds__(256) void scan_apply(const float* __restrict__ delta,
                                                  const float* __restrict__ a,
                                                  const float* __restrict__ bcd,
                                                  const float* __restrict__ ab,
                                                  const float* __restrict__ A_log,
                                                  const float* __restrict__ Dp,
                                                  const float* __restrict__ Hb,
                                                  float* __restrict__ y1,
                                                  unsigned short* __restrict__ y1b) {
    int bid = blockIdx.x;
    int c = bid & (NC - 1);
    int dblk = (bid >> 5) % (DM / 16);
    int b = bid / (NC * (DM / 16));
    int s = threadIdx.x & 15, dl = threadIdx.x >> 4;
    int d = dblk * 16 + dl;
    float An = -expf(A_log[d * DS + s]);
    float Dv = Dp[d];
    int g = (b * DM + d) * 16 + s;
    float h = Hb[c * NG + g];
    int t0 = b * SEQLEN + c * CL;
    for (int l = 0; l < CL; l++) {
        int t = t0 + l;
        float dv = delta[(size_t)t * DM + d];
        float av = a[(size_t)t * DM + d];
        float Bv = bcd[t * 128 + s];
        float Cv = bcd[t * 128 + 16 + s];
        h = expf(dv * An) * h + dv * Bv * av;
        float ct = h * Cv;
        ct += __shfl_xor(ct, 1);
        ct += __shfl_xor(ct, 2);
        ct += __shfl_xor(ct, 4);
        ct += __shfl_xor(ct, 8);
        if (s == 0) {
            float bg = ab[(size_t)t * 2 * DM + DM + d];
            float sl = bg / (1.f + expf(-bg));
            float y = (ct + Dv * av) * sl;
            y1[(size_t)t * DM + d] = y;
            y1b[(size_t)t * DM + d] = f2bf(y);
        }
    }
}

extern "C" void kernel_launch(void* const* d_in, const int* in_sizes, int n_in,
                              void* d_out, int out_size, void* d_ws, size_t ws_size,
                              hipStream_t stream) {
    const int* tok        = (const int*)d_in[0];
    const float* emb      = (const float*)d_in[1];
    const float* in_proj  = (const float*)d_in[2];   // (4, 3072, 768)
    const float* out_proj = (const float*)d_in[3];   // (4, 768, 1536)
    const float* sB       = (const float*)d_in[4];   // (4, 16, 1536)
    const float* sC       = (const float*)d_in[5];   // (4, 16, 1536)
    const float* sD0      = (const float*)d_in[6];   // (4, 96, 1536)
    const float* sD1      = (const float*)d_in[7];   // (4, 1536, 96)
    const float* sD1b     = (const float*)d_in[8];   // (4, 1536)
    const float* cw       = (const float*)d_in[9];   // (4, 1536, 4)
    const float* cb       = (const float*)d_in[10];  // (4, 1536)
    const float* A_log    = (const float*)d_in[11];  // (4, 1536, 16)
    const float* Dp       = (const float*)d_in[12];  // (4, 1536)
    const float* norm_w   = (const float*)d_in[13];  // (4, 768)
    const float* norm_f   = (const float*)d_in[14];  // (768,)
    const float* head_w   = (const float*)d_in[15];  // (32000, 768)
    float* out = (float*)d_out;

    char* base = (char*)d_ws;
    float* seq   = (float*)base;          base += (size_t)NTOK * DIN * 4;
    float* ab    = (float*)base;          base += (size_t)NTOK * 2 * DM * 4;   // head_bf aliases from here
    float* ac    = (float*)base;          base += (size_t)NTOK * DM * 4;
    float* delta = (float*)base;          base += (size_t)NTOK * DM * 4;
    float* y1    = (float*)base;          base += (size_t)NTOK * DM * 4;
    float* bcd   = (float*)base;          base += (size_t)NTOK * 128 * 4;
    unsigned short* xnb  = (unsigned short*)base;  base += (size_t)NTOK * DIN * 2;
    unsigned short* acb  = (unsigned short*)base;  base += (size_t)NTOK * DM * 2;
    unsigned short* y1b  = (unsigned short*)base;  base += (size_t)NTOK * DM * 2;
    float* P  = (float*)base;             base += (size_t)NG * NC * 4;
    float* S  = (float*)base;             base += (size_t)NG * NC * 4;
    float* Hb = (float*)base;             base += (size_t)NG * NC * 4;
    unsigned short* inpb  = (unsigned short*)base; base += (size_t)4 * 2 * DM * DIN * 2;
    unsigned short* outpb = (unsigned short*)base; base += (size_t)4 * DIN * DM * 2;
    unsigned short* wcatb = (unsigned short*)base; base += (size_t)4 * 128 * DM * 2;
    // head bf16 weights alias the (dead-by-then) ab+ac+delta region: 49.2 MB < 50.3 MB
    unsigned short* headb = (unsigned short*)ab;

    embed_kernel<<<NTOK, 192, 0, stream>>>(tok, emb, seq);
    cast_kernel<<<(4 * 2 * DM * DIN / 4 + 255) / 256, 256, 0, stream>>>(in_proj, inpb, 4 * 2 * DM * DIN / 4);
    cast_kernel<<<(4 * DIN * DM / 4 + 255) / 256, 256, 0, stream>>>(out_proj, outpb, 4 * DIN * DM / 4);
    wcat_kernel<<<4 * 128 * DM / 256, 256, 0, stream>>>(sB, sC, sD0, wcatb);

    for (int i = 0; i < 4; i++) {
        rmsnorm_kernel<<<NTOK, 256, 0, stream>>>(seq, norm_w + i * DIN, xnb);
        gemm_mfma<0><<<dim3(2 * DM / 128, NTOK / 128), 256, 0, stream>>>(
            xnb, inpb + (size_t)i * 2 * DM * DIN, ab, 2 * DM, DIN);
        conv_silu_kernel<<<NTOK * DM / 256, 256, 0, stream>>>(
            ab, cw + (size_t)i * DM * 4, cb + (size_t)i * DM, ac, acb);
        gemm_mfma<0><<<dim3(1, NTOK / 128), 256, 0, stream>>>(
            acb, wcatb + (size_t)i * 128 * DM, bcd, 128, DM);
        gemm32_softplus<<<dim3(DM / 64, NTOK / 64), 256, 0, stream>>>(
            bcd + 32, 128, sD1 + (size_t)i * DM * DD, delta, DM, DD, sD1b + (size_t)i * DM);
        scan_chunk<<<BATCH * (DM / 16) * NC, 256, 0, stream>>>(
            delta, ac, bcd, A_log + (size_t)i * DM * DS, P, S);
        scan_combine<<<NG / 256, 256, 0, stream>>>(P, S, Hb);
        scan_apply<<<BATCH * (DM / 16) * NC, 256, 0, stream>>>(
            delta, ac, bcd, ab, A_log + (size_t)i * DM * DS, Dp + (size_t)i * DM, Hb, y1, y1b);
        gemm_mfma<1><<<dim3(DIN / 128, NTOK / 128), 256, 0, stream>>>(
            y1b, outpb + (size_t)i * DIN * DM, seq, DIN, DM);
    }
    rmsnorm_kernel<<<NTOK, 256, 0, stream>>>(seq, norm_f, xnb);
    cast_kernel<<<(32000 * DIN / 4 + 255) / 256, 256, 0, stream>>>(head_w, headb, 32000 * DIN / 4);
    gemm_mfma<0><<<dim3(32000 / 128, NTOK / 128), 256, 0, stream>>>(
        xnb, headb, out, 32000, DIN);
}